// Round 2
// baseline (253.175 us; speedup 1.0000x reference)
//
#include <hip/hip_runtime.h>
#include <stdint.h>
#include <stddef.h>

#define NQ 384
#define NK 384

typedef __attribute__((ext_vector_type(4))) float float4_;
typedef __attribute__((ext_vector_type(8))) short short8;

__device__ __forceinline__ short f2bf(float f) {
  union { float f; uint32_t u; } v; v.f = f;
  uint32_t u = v.u;
  uint32_t r = (u + 0x7fffu + ((u >> 16) & 1u)) >> 16;
  return (short)r;
}

// ---------------- prep kernel: A1/A2 + weight fragment packing ----------------
// blocks 0..1535  : A1[b,q,:] = (q_inv@Wq + bq) @ W1[0:64] + b1
// blocks 1536..3071: A2[b,k,:] = (k_inv@Wk + bk) @ W1[64:128]
// block 3072      : pack W1[128:192] and W2 into MFMA B-fragment order (bf16)
__global__ __launch_bounds__(128) void prep_kernel(
    const float* __restrict__ q_inv, const float* __restrict__ k_inv,
    const float* __restrict__ Wq, const float* __restrict__ bq,
    const float* __restrict__ Wk, const float* __restrict__ bk,
    const float* __restrict__ W1, const float* __restrict__ b1,
    const float* __restrict__ W2,
    float* __restrict__ A1, float* __restrict__ A2,
    short* __restrict__ W1dfrag, short* __restrict__ W2frag)
{
  int bid = blockIdx.x;
  int t = threadIdx.x;

  if (bid == 3072) {
    // B-frag layout: lane l holds col j=(l&15), k = (l>>4)*8 + i
    for (int idx = t; idx < 8192; idx += 128) {
      int fi = idx >> 9;          // fragment index
      int l  = (idx >> 3) & 63;   // lane
      int i  = idx & 7;
      // W1d frags: fi = n*2+s, n in 0..7, s in 0..1 (K=64)
      {
        int n = fi >> 1, s = fi & 1;
        int d = s * 32 + ((l >> 4) << 3) + i;
        int f = n * 16 + (l & 15);
        W1dfrag[idx] = f2bf(W1[(128 + d) * 128 + f]);
      }
      // W2 frags: fi = n2*4+s2, n2 in 0..3, s2 in 0..3 (K=128)
      {
        int n2 = fi >> 2, s2 = fi & 3;
        int k = s2 * 32 + ((l >> 4) << 3) + i;
        int o = n2 * 16 + (l & 15);
        W2frag[idx] = f2bf(W2[k * 64 + o]);
      }
    }
    return;
  }

  int half = bid / 1536;           // 0 -> q side, 1 -> k side
  int idx = bid - half * 1536;     // b*384 + row
  const float* inv  = (half ? k_inv : q_inv) + (size_t)idx * 256;
  const float* W    = half ? Wk : Wq;
  const float* bias = half ? bk : bq;

  __shared__ float sinv[256];
  __shared__ float part[2][64];
  __shared__ float smsg[64];

  sinv[t] = inv[t];
  sinv[t + 128] = inv[t + 128];
  __syncthreads();

  {
    int f = t & 63, hh = t >> 6;
    float acc = 0.f;
    const float* wp = W + hh * 128 * 64 + f;
    const float* ip = sinv + hh * 128;
    #pragma unroll 4
    for (int j = 0; j < 128; ++j) acc += ip[j] * wp[j * 64];
    part[hh][f] = acc;
  }
  __syncthreads();
  if (t < 64) smsg[t] = part[0][t] + part[1][t] + bias[t];
  __syncthreads();

  {
    int n = t;  // 0..127
    const float* w1p = W1 + (half ? 64 : 0) * 128 + n;
    float acc = half ? 0.f : b1[n];
    #pragma unroll 8
    for (int f = 0; f < 64; ++f) acc += smsg[f] * w1p[f * 128];
    (half ? A2 : A1)[(size_t)idx * 128 + n] = acc;
  }
}

// ---------------- main fused kernel ----------------
// one block = (b, 16 q rows, 16 k rows) = 256 pairs; 8 waves; wave w owns qi in {2w, 2w+1}
__global__ __launch_bounds__(512) void main_kernel(
    const float* __restrict__ q_equi, const float* __restrict__ k_equi,
    const float* __restrict__ A1, const float* __restrict__ A2,
    const short* __restrict__ W1dfrag, const short* __restrict__ W2frag,
    const float* __restrict__ b2, float* __restrict__ out)
{
  int bid = blockIdx.x;
  int b = bid / 576;
  int rem = bid - b * 576;
  int tq = rem / 24, tk = rem - (rem / 24) * 24;
  int q0 = tq * 16, k0 = tk * 16;

  __shared__ __align__(16) char smem[65536];
  float* sQ = (float*)smem;                 // [3][16][68] fp32
  float* sK = (float*)(smem + 13056);       // [3][16][68] fp32
  // later phases alias smem as swizzled bf16 h[256][128]

  int tid = threadIdx.x;
  int w = tid >> 6, l = tid & 63;
  int g = l >> 4, r16 = l & 15;

  // ---- stage equi tiles (contiguous 3072 floats each) ----
  const float* qsrc = q_equi + ((size_t)(b * NQ + q0)) * 192;
  const float* ksrc = k_equi + ((size_t)(b * NK + k0)) * 192;
  for (int j = tid; j < 3072; j += 512) {
    int rr = j / 192, cd = j - rr * 192;
    int c = cd >> 6, d = cd & 63;
    int li = c * 1088 + rr * 68 + d;   // pad rows to 68 -> conflict-free-ish b128 reads
    sQ[li] = qsrc[j];
    sK[li] = ksrc[j];
  }
  __syncthreads();

  // ---- build dotprod A-fragments directly in registers ----
  // A-frag (16x16x32): lane l holds row (l&15)=ki, k = s*32 + (l>>4)*8 + i
  short8 afrag[2][2];
  #pragma unroll
  for (int s = 0; s < 2; ++s) {
    int d0 = s * 32 + g * 8;
    float4_ kva[3], kvb[3];
    #pragma unroll
    for (int c = 0; c < 3; ++c) {
      kva[c] = *(const float4_*)&sK[c * 1088 + r16 * 68 + d0];
      kvb[c] = *(const float4_*)&sK[c * 1088 + r16 * 68 + d0 + 4];
    }
    #pragma unroll
    for (int m = 0; m < 2; ++m) {
      int qi = 2 * w + m;
      float4_ qva[3], qvb[3];
      #pragma unroll
      for (int c = 0; c < 3; ++c) {
        qva[c] = *(const float4_*)&sQ[c * 1088 + qi * 68 + d0];
        qvb[c] = *(const float4_*)&sQ[c * 1088 + qi * 68 + d0 + 4];
      }
      short8 af;
      #pragma unroll
      for (int i = 0; i < 4; ++i) {
        float da = qva[0][i] * kva[0][i] + qva[1][i] * kva[1][i] + qva[2][i] * kva[2][i];
        float db = qvb[0][i] * kvb[0][i] + qvb[1][i] * kvb[1][i] + qvb[2][i] * kvb[2][i];
        af[i]     = f2bf(da);
        af[i + 4] = f2bf(db);
      }
      afrag[m][s] = af;
    }
  }

  // ---- GEMM1: acc = A1 + A2 + D @ W1d   (M=16/wave-block, N=128, K=64) ----
  float4_ acc1[2][8];
  const float* A1p = A1 + ((size_t)(b * NQ + q0)) * 128;
  const float* A2p = A2 + ((size_t)(b * NK + k0)) * 128;
  #pragma unroll
  for (int n = 0; n < 8; ++n) {
    int f = n * 16 + r16;
    float a2v0 = A2p[(g * 4 + 0) * 128 + f];
    float a2v1 = A2p[(g * 4 + 1) * 128 + f];
    float a2v2 = A2p[(g * 4 + 2) * 128 + f];
    float a2v3 = A2p[(g * 4 + 3) * 128 + f];
    #pragma unroll
    for (int m = 0; m < 2; ++m) {
      float a1v = A1p[(2 * w + m) * 128 + f];
      acc1[m][n] = (float4_){a1v + a2v0, a1v + a2v1, a1v + a2v2, a1v + a2v3};
    }
  }
  #pragma unroll
  for (int n = 0; n < 8; ++n) {
    #pragma unroll
    for (int s = 0; s < 2; ++s) {
      short8 bf = *(const short8*)&W1dfrag[(((n * 2 + s) * 64) + l) * 8];
      #pragma unroll
      for (int m = 0; m < 2; ++m)
        acc1[m][n] = __builtin_amdgcn_mfma_f32_16x16x32_bf16(afrag[m][s], bf, acc1[m][n], 0, 0, 0);
    }
  }
  __syncthreads();   // equi-tile reads done; smem becomes h buffer

  // ---- silu -> bf16 h into swizzled LDS ----
  // C/D layout: col = l&15, row = (l>>4)*4 + reg ; h row = pair p, col = feature f
  #pragma unroll
  for (int m = 0; m < 2; ++m) {
    int pbase = (2 * w + m) * 16 + g * 4;
    #pragma unroll
    for (int n = 0; n < 8; ++n) {
      int col = n * 16 + r16;
      #pragma unroll
      for (int rr = 0; rr < 4; ++rr) {
        float x = acc1[m][n][rr];
        float sig = 1.f / (1.f + __expf(-x));
        int p = pbase + rr;
        int byte = (p * 256 + col * 2) ^ ((p & 7) << 4);
        *(short*)(smem + byte) = f2bf(x * sig);
      }
    }
  }
  __syncthreads();

  // ---- GEMM2: out = h @ W2 + b2   (K=128, N=64) ----
  short8 w2f[4][4];
  #pragma unroll
  for (int n2 = 0; n2 < 4; ++n2)
    #pragma unroll
    for (int s2 = 0; s2 < 4; ++s2)
      w2f[n2][s2] = *(const short8*)&W2frag[(((n2 * 4 + s2) * 64) + l) * 8];

  float4_ acc2[2][4];
  #pragma unroll
  for (int m = 0; m < 2; ++m)
    #pragma unroll
    for (int n2 = 0; n2 < 4; ++n2)
      acc2[m][n2] = (float4_){0.f, 0.f, 0.f, 0.f};

  #pragma unroll
  for (int m = 0; m < 2; ++m) {
    int row = (2 * w + m) * 16 + r16;
    #pragma unroll
    for (int s2 = 0; s2 < 4; ++s2) {
      int byte = (row * 256 + (s2 * 32 + g * 8) * 2) ^ ((row & 7) << 4);
      short8 ha = *(const short8*)(smem + byte);
      #pragma unroll
      for (int n2 = 0; n2 < 4; ++n2)
        acc2[m][n2] = __builtin_amdgcn_mfma_f32_16x16x32_bf16(ha, w2f[n2][s2], acc2[m][n2], 0, 0, 0);
    }
  }

  // ---- epilogue ----
  float* outp = out + ((size_t)(b * NQ + q0) * NK + k0) * 64;
  #pragma unroll
  for (int n2 = 0; n2 < 4; ++n2) {
    float b2v = b2[n2 * 16 + r16];
    #pragma unroll
    for (int m = 0; m < 2; ++m) {
      int qi = 2 * w + m;
      #pragma unroll
      for (int rr = 0; rr < 4; ++rr) {
        int ki = g * 4 + rr;
        outp[((size_t)qi * NK + ki) * 64 + n2 * 16 + r16] = acc2[m][n2][rr] + b2v;
      }
    }
  }
}

extern "C" void kernel_launch(void* const* d_in, const int* in_sizes, int n_in,
                              void* d_out, int out_size, void* d_ws, size_t ws_size,
                              hipStream_t stream) {
  (void)in_sizes; (void)n_in; (void)out_size; (void)ws_size;
  const float* q_equi = (const float*)d_in[0];
  const float* q_inv  = (const float*)d_in[1];
  const float* k_equi = (const float*)d_in[2];
  const float* k_inv  = (const float*)d_in[3];
  const float* Wq = (const float*)d_in[4];
  const float* bq = (const float*)d_in[5];
  const float* Wk = (const float*)d_in[6];
  const float* bk = (const float*)d_in[7];
  const float* W1 = (const float*)d_in[8];
  const float* b1 = (const float*)d_in[9];
  const float* W2 = (const float*)d_in[10];
  const float* b2 = (const float*)d_in[11];
  float* out = (float*)d_out;

  char* ws = (char*)d_ws;
  float* A1      = (float*)(ws);               // 786432 B
  float* A2      = (float*)(ws + 786432);      // 786432 B
  short* W1dfrag = (short*)(ws + 1572864);     // 16384 B
  short* W2frag  = (short*)(ws + 1589248);     // 16384 B

  prep_kernel<<<3073, 128, 0, stream>>>(q_inv, k_inv, Wq, bq, Wk, bk, W1, b1, W2,
                                        A1, A2, W1dfrag, W2frag);
  main_kernel<<<2304, 512, 0, stream>>>(q_equi, k_equi, A1, A2, W1dfrag, W2frag, b2, out);
}